// Round 5
// baseline (255.206 us; speedup 1.0000x reference)
//
#include <hip/hip_runtime.h>

// S4 -> causal conv. y[b,t] = d*u0[b,t] + sum_j k[j]*u0[b,t-j], k[j]=c^T Abar^j bbar.
// Abar = expm(dt*A): scale (theta=2) + Taylor-15 Paterson-Stockmeyer + squarings.
// bbar = dt*phi1(dtA)B: phi1 by PS on vectors + doubling through the squarings.
// k = CQ^T BR bilinear split; BR/CQ stored transposed (rows) in LDS.
//
// THIS REVISION: the entire setup chain runs on ONE WAVE (64 lanes), zero
// __syncthreads. All matrices live in 6 LDS slots (105 KB); MFMA fragments are
// loaded directly from f32 LDS and converted to bf16 hi/lo IN REGISTERS (no
// FRAG staging). Intra-wave LDS ordering is compiler-inserted lgkmcnt; in-place
// matmuls are safe because all fragment loads precede all stores in program
// order. Fragment lane mappings identical to the r2-verified 4-wave kernel:
//   A/B 16x16x32: row/col = l&15, k = (l>>4)*8 + j (per 32-k half)
//   C/D: col = l&15, row-group = (l>>4)*4 + i
// MFMA order per tile: Ah0Bh0, Ah1Bh1, Ah0Bl0, Ah1Bl1, Al0Bh0, Al1Bh1 (same).
//
// ws floats: [0,4096) k | [4096,20480) u0   (81920 B used)

#define NT 256
#define MP 68
#define MB (64 * MP)

typedef __attribute__((ext_vector_type(8))) short v8s;
typedef __attribute__((ext_vector_type(4))) float v4f;

__device__ __forceinline__ unsigned short bf16r(float x) {
  union { float f; unsigned u; } v; v.f = x;
  unsigned r = v.u + 0x7fffu + ((v.u >> 16) & 1u);
  return (unsigned short)(r >> 16);
}
__device__ __forceinline__ float bf2f(unsigned short h) {
  union { unsigned u; float f; } v; v.u = ((unsigned)h) << 16;
  return v.f;
}
__device__ __forceinline__ void cvt4(const float4 f, ushort4* H, ushort4* L) {
  unsigned short h;
  h = bf16r(f.x); H->x = h; L->x = bf16r(f.x - bf2f(h));
  h = bf16r(f.y); H->y = h; L->y = bf16r(f.y - bf2f(h));
  h = bf16r(f.z); H->z = h; L->z = bf16r(f.z - bf2f(h));
  h = bf16r(f.w); H->w = h; L->w = bf16r(f.w - bf2f(h));
}
__device__ __forceinline__ void cvt8(const float4 f0, const float4 f1,
                                     v8s* H, v8s* L) {
  union { v8s v; ushort4 u[2]; } Hu, Lu;
  cvt4(f0, &Hu.u[0], &Lu.u[0]);
  cvt4(f1, &Hu.u[1], &Lu.u[1]);
  *H = Hu.v; *L = Lu.v;
}

// Single-wave 64x64 matmul: C[rowbase+i][j] = sum_k A[i][k]*B[k][j], i<16*NRT.
// A rows 0..16*NRT from As (LDS, pitch MP). BT=0: B[k][n]=Bs[k*MP+n];
// BT=1: B[k][n]=Bs[n*MP+k]. Cd pitch cpitch (LDS or global); Cd2 optional
// extra copy (pitch MP). In-place safe (loads precede stores, single wave).
template<int NRT, int BT>
__device__ __attribute__((noinline)) void mm1w(const int l, const float* As,
    const float* Bs, float* Cd, const int cpitch, const int rowbase,
    float* Cd2) {
  const int m = l & 15;
  const int g = l >> 4;
  v8s Ah[NRT][2], Al[NRT][2];
#pragma unroll
  for (int rt = 0; rt < NRT; ++rt)
#pragma unroll
    for (int h = 0; h < 2; ++h) {
      const float* ap = As + (rt * 16 + m) * MP + h * 32 + g * 8;
      cvt8(*(const float4*)ap, *(const float4*)(ap + 4), &Ah[rt][h], &Al[rt][h]);
    }
  v4f acc[NRT][4];
#pragma unroll
  for (int rt = 0; rt < NRT; ++rt)
#pragma unroll
    for (int ct = 0; ct < 4; ++ct) acc[rt][ct] = (v4f){0.f, 0.f, 0.f, 0.f};
#pragma unroll
  for (int ct = 0; ct < 4; ++ct) {
    v8s Bh[2], Bl[2];
#pragma unroll
    for (int h = 0; h < 2; ++h) {
      float4 g0, g1;
      if (BT) {
        const float* bp = Bs + (ct * 16 + m) * MP + h * 32 + g * 8;
        g0 = *(const float4*)bp;
        g1 = *(const float4*)(bp + 4);
      } else {
        const int kb = h * 32 + g * 8;
        const int cc = ct * 16 + m;
        g0.x = Bs[(kb + 0) * MP + cc]; g0.y = Bs[(kb + 1) * MP + cc];
        g0.z = Bs[(kb + 2) * MP + cc]; g0.w = Bs[(kb + 3) * MP + cc];
        g1.x = Bs[(kb + 4) * MP + cc]; g1.y = Bs[(kb + 5) * MP + cc];
        g1.z = Bs[(kb + 6) * MP + cc]; g1.w = Bs[(kb + 7) * MP + cc];
      }
      cvt8(g0, g1, &Bh[h], &Bl[h]);
    }
#pragma unroll
    for (int rt = 0; rt < NRT; ++rt) {
      v4f a = acc[rt][ct];
      a = __builtin_amdgcn_mfma_f32_16x16x32_bf16(Ah[rt][0], Bh[0], a, 0, 0, 0);
      a = __builtin_amdgcn_mfma_f32_16x16x32_bf16(Ah[rt][1], Bh[1], a, 0, 0, 0);
      a = __builtin_amdgcn_mfma_f32_16x16x32_bf16(Ah[rt][0], Bl[0], a, 0, 0, 0);
      a = __builtin_amdgcn_mfma_f32_16x16x32_bf16(Ah[rt][1], Bl[1], a, 0, 0, 0);
      a = __builtin_amdgcn_mfma_f32_16x16x32_bf16(Al[rt][0], Bh[0], a, 0, 0, 0);
      a = __builtin_amdgcn_mfma_f32_16x16x32_bf16(Al[rt][1], Bh[1], a, 0, 0, 0);
      acc[rt][ct] = a;
    }
  }
#pragma unroll
  for (int rt = 0; rt < NRT; ++rt)
#pragma unroll
    for (int ct = 0; ct < 4; ++ct) {
      const int col = ct * 16 + m;
      const int r0 = rowbase + rt * 16 + g * 4;
#pragma unroll
      for (int i = 0; i < 4; ++i) {
        const float o = acc[rt][ct][i];
        Cd[(size_t)(r0 + i) * cpitch + col] = o;
        if (Cd2) Cd2[(r0 + i) * MP + col] = o;
      }
    }
}

// lane l returns dot(M[l][:], VV[:]) -- M pitch MP, VV 64 floats in LDS.
__device__ __forceinline__ float dotrow1w(const int l, const float* M,
                                          const float* VV) {
  const float* mp = M + l * MP;
  float pa = 0.f, pb = 0.f, pc = 0.f, pd = 0.f;
#pragma unroll
  for (int jq = 0; jq < 16; ++jq) {
    const float4 m4 = *(const float4*)(mp + jq * 4);
    const float4 w4 = *(const float4*)(VV + jq * 4);
    pa = fmaf(m4.x, w4.x, pa);
    pb = fmaf(m4.y, w4.y, pb);
    pc = fmaf(m4.z, w4.z, pc);
    pd = fmaf(m4.w, w4.w, pd);
  }
  return (pa + pb) + (pc + pd);
}

// lane l returns dot(M[:][l], VV[:]) (column dot; conflict-free scalar reads).
__device__ __forceinline__ float dotcol1w(const int l, const float* M,
                                          const float* VV) {
  float pa = 0.f, pb = 0.f, pc = 0.f, pd = 0.f;
#pragma unroll
  for (int j = 0; j < 64; j += 4) {
    pa = fmaf(M[(j + 0) * MP + l], VV[j + 0], pa);
    pb = fmaf(M[(j + 1) * MP + l], VV[j + 1], pb);
    pc = fmaf(M[(j + 2) * MP + l], VV[j + 2], pc);
    pd = fmaf(M[(j + 3) * MP + l], VV[j + 3], pd);
  }
  return (pa + pb) + (pc + pd);
}

// dst = c0*I + c1*X + c2*X2 + c3*X3 (+ addsrc). Lane l handles float4s l+64i.
__device__ __forceinline__ void buildG1w(const int l, float* dst, const float* X,
    const float* X2, const float* X3, const float c0, const float c1,
    const float c2, const float c3, const float* addsrc) {
#pragma unroll
  for (int i = 0; i < 16; ++i) {
    const int f = l + (i << 6);
    const int r = f >> 4;
    const int c = (f & 15) * 4;
    const int e = r * MP + c;
    const float4 x1 = *(const float4*)(X + e);
    const float4 x2 = *(const float4*)(X2 + e);
    const float4 x3 = *(const float4*)(X3 + e);
    float4 v;
    v.x = fmaf(c1, x1.x, fmaf(c2, x2.x, c3 * x3.x));
    v.y = fmaf(c1, x1.y, fmaf(c2, x2.y, c3 * x3.y));
    v.z = fmaf(c1, x1.z, fmaf(c2, x2.z, c3 * x3.z));
    v.w = fmaf(c1, x1.w, fmaf(c2, x2.w, c3 * x3.w));
    if (r == c + 0) v.x += c0;
    if (r == c + 1) v.y += c0;
    if (r == c + 2) v.z += c0;
    if (r == c + 3) v.w += c0;
    if (addsrc) {
      const float4 a = *(const float4*)(addsrc + e);
      v.x += a.x; v.y += a.y; v.z += a.z; v.w += a.w;
    }
    *(float4*)(dst + e) = v;
  }
}

__global__ __launch_bounds__(NT, 1) void s4_setup(const float* __restrict__ u,
    const float* __restrict__ A, const float* __restrict__ Bv,
    const float* __restrict__ Cv, const float* __restrict__ logdt,
    float* __restrict__ ws) {
  if (blockIdx.x > 0) {
    const int idx = (blockIdx.x - 1) * NT + threadIdx.x;  // 0..16383
    ws[4096 + idx] = u[(size_t)idx * 1024];
    return;
  }
  // 6 matrix slots (64 x MP f32 each, 17408 B) + one 64-f32 vector buffer.
  __shared__ __align__(16) float SH[MB];    // hot slot (X, X2, X4, e^X, powers)
  __shared__ __align__(16) float SXs[MB];   // X
  __shared__ __align__(16) float SX2s[MB];  // X2
  __shared__ __align__(16) float SX3s[MB];  // X3
  __shared__ __align__(16) float SU0s[MB];  // Horner U0; later BRT
  __shared__ __align__(16) float SU1s[MB];  // Horner U1; later CQT
  __shared__ __align__(16) float VV[64];

  const int t = threadIdx.x;
  if (t >= 64) return;  // single wave does everything; no barriers anywhere
  const int l = t;

  float* kbuf = ws;
  float* SBRT = SU0s;
  float* SCQT = SU1s;
  const float dt = expf(logdt[0]);

  const float invf[17] = {1.f, 1.f, 1.f / 2.f, 1.f / 6.f, 1.f / 24.f, 1.f / 120.f,
                          1.f / 720.f, 1.f / 5040.f, 1.f / 40320.f, 1.f / 362880.f,
                          1.f / 3628800.f, 1.f / 39916800.f, 1.f / 479001600.f,
                          1.f / 6.2270208e9f, 1.f / 8.71782912e10f,
                          1.f / 1.307674368e12f, 1.f / 2.0922789888e13f};

  // ---- stage raw A -> SH (coalesced global float4) ----
#pragma unroll
  for (int i = 0; i < 16; ++i) {
    const int f = l + (i << 6);
    const float4 a4 = *(const float4*)(A + f * 4);
    *(float4*)(SH + (f >> 4) * MP + (f & 15) * 4) = a4;
  }

  // ---- 1-norm of dt*A -> sq (theta = 2); lane l sums |col l| ----
  float csum = 0.f;
#pragma unroll 8
  for (int r = 0; r < 64; ++r) csum += fabsf(SH[r * MP + l]);
  float cs = csum * dt;
#pragma unroll
  for (int off = 32; off > 0; off >>= 1) cs = fmaxf(cs, __shfl_xor(cs, off));
  int sq = 0;
  while (cs > 2.0f && sq < 30) { cs *= 0.5f; ++sq; }
  const float scl = ldexpf(dt, -sq);

  // ---- X = scl*A -> SH (in-place) and SXs ----
#pragma unroll
  for (int i = 0; i < 16; ++i) {
    const int f = l + (i << 6);
    const int e = (f >> 4) * MP + (f & 15) * 4;
    float4 x = *(const float4*)(SH + e);
    x.x *= scl; x.y *= scl; x.z *= scl; x.w *= scl;
    *(float4*)(SH + e) = x;
    *(float4*)(SXs + e) = x;
  }
  const float vBr = Bv[l];

  // ---- powers: X2 (SH, copy SX2), X3 (SX3), X4 (SH in-place) ----
  mm1w<4, 0>(l, SH, SH, SH, MP, 0, SX2s);      // X2
  mm1w<4, 0>(l, SXs, SH, SX3s, MP, 0, nullptr);  // X3 = X*X2
  mm1w<4, 0>(l, SH, SH, SH, MP, 0, nullptr);   // X4 = X2*X2

  // ---- phi1(X)*B via PS on vectors (deg-15, groups of 4 in X4) ----
  VV[l] = vBr;
  const float v1r = dotrow1w(l, SXs, VV);
  const float v2r = dotrow1w(l, SX2s, VV);
  const float v3r = dotrow1w(l, SX3s, VV);
  float var = invf[13] * vBr + invf[14] * v1r + invf[15] * v2r + invf[16] * v3r;
  VV[l] = var;
  float vbr = dotrow1w(l, SH, VV);
  var = invf[9] * vBr + invf[10] * v1r + invf[11] * v2r + invf[12] * v3r + vbr;
  VV[l] = var;
  vbr = dotrow1w(l, SH, VV);
  var = invf[5] * vBr + invf[6] * v1r + invf[7] * v2r + invf[8] * v3r + vbr;
  VV[l] = var;
  vbr = dotrow1w(l, SH, VV);
  float vgr = invf[1] * vBr + invf[2] * v1r + invf[3] * v2r + invf[4] * v3r + vbr;

  // ---- e^X: Taylor-15 PS Horner (B-operand X4 in SH) ----
  buildG1w(l, SU0s, SXs, SX2s, SX3s, invf[12], invf[13], invf[14], invf[15], nullptr);
  mm1w<4, 0>(l, SU0s, SH, SU1s, MP, 0, nullptr);
  buildG1w(l, SU1s, SXs, SX2s, SX3s, invf[8], invf[9], invf[10], invf[11], SU1s);
  mm1w<4, 0>(l, SU1s, SH, SU0s, MP, 0, nullptr);
  buildG1w(l, SU0s, SXs, SX2s, SX3s, invf[4], invf[5], invf[6], invf[7], SU0s);
  mm1w<4, 0>(l, SU0s, SH, SH, MP, 0, nullptr);   // -> SH (over X4)
  buildG1w(l, SH, SXs, SX2s, SX3s, invf[0], invf[1], invf[2], invf[3], SH);
  // SH = e^X

  // ---- squarings + phi1 doubling: g <- (F+I)g/2 ----
  float cur = vgr;
  for (int it = 0; it < sq; ++it) {
    VV[l] = cur;
    const float p = dotrow1w(l, SH, VV);
    cur = 0.5f * (p + cur);
    mm1w<4, 0>(l, SH, SH, SH, MP, 0, nullptr);
  }
  // SH = Abar, cur = phi1 vector

  // ---- BRT rows 0..15: bbar then Abar^r bbar ----
  float bcur = dt * cur;
  SBRT[l] = bcur;
  for (int r = 1; r < 16; ++r) {
    VV[l] = bcur;
    bcur = dotrow1w(l, SH, VV);
    SBRT[r * MP + l] = bcur;
  }

  // ---- P-chain (in-place) + BRT widenings ----
  mm1w<4, 0>(l, SH, SH, SH, MP, 0, nullptr);        // P2
  mm1w<4, 0>(l, SH, SH, SH, MP, 0, nullptr);        // P4
  mm1w<4, 0>(l, SH, SH, SH, MP, 0, nullptr);        // P8
  mm1w<4, 0>(l, SH, SH, SH, MP, 0, nullptr);        // P16
  mm1w<1, 1>(l, SBRT, SH, SBRT, MP, 16, nullptr);   // rows16:32 = BRT0:16*P16^T
  mm1w<4, 0>(l, SH, SH, SH, MP, 0, nullptr);        // P32
  mm1w<2, 1>(l, SBRT, SH, SBRT, MP, 32, nullptr);   // rows32:64
  mm1w<4, 0>(l, SH, SH, SH, MP, 0, nullptr);        // P64

  // ---- CQT rows 0..15: c then (P64^T)^q c ----
  float ccur = Cv[l];
  SCQT[l] = ccur;
  for (int qx = 1; qx < 16; ++qx) {
    VV[l] = ccur;
    ccur = dotcol1w(l, SH, VV);
    SCQT[qx * MP + l] = ccur;
  }

  // ---- A-chain (in-place) + CQT widenings ----
  mm1w<4, 0>(l, SH, SH, SH, MP, 0, nullptr);        // A128
  mm1w<4, 0>(l, SH, SH, SH, MP, 0, nullptr);        // A256
  mm1w<4, 0>(l, SH, SH, SH, MP, 0, nullptr);        // A512
  mm1w<4, 0>(l, SH, SH, SH, MP, 0, nullptr);        // A1024
  mm1w<1, 0>(l, SCQT, SH, SCQT, MP, 16, nullptr);   // rows16:32 = CQT0:16*A1024
  mm1w<4, 0>(l, SH, SH, SH, MP, 0, nullptr);        // A2048
  mm1w<2, 0>(l, SCQT, SH, SCQT, MP, 32, nullptr);   // rows32:64

  // ---- k[q*64+r] = sum_i CQT[q][i]*BRT[r][i] (global, pitch 64) ----
  mm1w<4, 1>(l, SCQT, SBRT, kbuf, 64, 0, nullptr);
}

// Fused conv + broadcast. 4096 blocks x 256 threads; block computes y[t0..t0+3]
// for one batch, then streams 4 rows x 1024 cols of broadcast stores.
// Conv: thread owns source chunks s0 = 4*tid + 1024*iter (16B-aligned since t0
// and s0 are multiples of 4). y[t0+d] += sum_i k[b0+d-i]*u[s0+i], b0=t0-s0;
// k indices d-i in [-3,3] served by two aligned float4 (k0=k[b0..b0+3],
// k1=k[b0-4..b0-1], zeroed at b0==0 which exactly masks the invalid terms).
__global__ __launch_bounds__(256) void s4_out(const float* __restrict__ ws,
                                              const float* __restrict__ Dp,
                                              float* __restrict__ out) {
  const int bid = blockIdx.x;
  const int b = bid >> 10;
  const int t0 = (bid & 1023) << 2;
  const float* kb = ws;
  const float* ub = ws + 4096 + (b << 12);
  const int tid = threadIdx.x;

  float a0 = 0.f, a1 = 0.f, a2 = 0.f, a3 = 0.f;
  for (int s0 = tid << 2; s0 <= t0; s0 += 1024) {
    const float4 uv = *(const float4*)(ub + s0);
    const int b0 = t0 - s0;  // multiple of 4, >= 0
    const float4 k0 = *(const float4*)(kb + b0);
    float4 k1 = make_float4(0.f, 0.f, 0.f, 0.f);
    if (b0 >= 4) k1 = *(const float4*)(kb + b0 - 4);
    a0 = fmaf(k0.x, uv.x, a0);
    a0 = fmaf(k1.w, uv.y, a0);
    a0 = fmaf(k1.z, uv.z, a0);
    a0 = fmaf(k1.y, uv.w, a0);
    a1 = fmaf(k0.y, uv.x, a1);
    a1 = fmaf(k0.x, uv.y, a1);
    a1 = fmaf(k1.w, uv.z, a1);
    a1 = fmaf(k1.z, uv.w, a1);
    a2 = fmaf(k0.z, uv.x, a2);
    a2 = fmaf(k0.y, uv.y, a2);
    a2 = fmaf(k0.x, uv.z, a2);
    a2 = fmaf(k1.w, uv.w, a2);
    a3 = fmaf(k0.w, uv.x, a3);
    a3 = fmaf(k0.z, uv.y, a3);
    a3 = fmaf(k0.y, uv.z, a3);
    a3 = fmaf(k0.x, uv.w, a3);
  }
#pragma unroll
  for (int off = 32; off > 0; off >>= 1) {
    a0 += __shfl_xor(a0, off);
    a1 += __shfl_xor(a1, off);
    a2 += __shfl_xor(a2, off);
    a3 += __shfl_xor(a3, off);
  }
  __shared__ float red[4][4];
  __shared__ float sy[4];
  if ((tid & 63) == 0) {
    const int w = tid >> 6;
    red[0][w] = a0; red[1][w] = a1; red[2][w] = a2; red[3][w] = a3;
  }
  __syncthreads();
  if (tid < 4)
    sy[tid] = red[tid][0] + red[tid][1] + red[tid][2] + red[tid][3] +
              Dp[0] * ub[t0 + tid];
  __syncthreads();
  const int row = tid >> 6, lx = tid & 63;
  const float y = sy[row];
  const v4f y4 = {y, y, y, y};
  v4f* dst = (v4f*)(out + ((size_t)(b << 12) + t0 + row) * 1024);
  __builtin_nontemporal_store(y4, dst + lx);
  __builtin_nontemporal_store(y4, dst + lx + 64);
  __builtin_nontemporal_store(y4, dst + lx + 128);
  __builtin_nontemporal_store(y4, dst + lx + 192);
}

extern "C" void kernel_launch(void* const* d_in, const int* in_sizes, int n_in,
                              void* d_out, int out_size, void* d_ws, size_t ws_size,
                              hipStream_t stream) {
  const float* u  = (const float*)d_in[0];
  const float* A  = (const float*)d_in[1];
  const float* B  = (const float*)d_in[2];
  const float* C  = (const float*)d_in[3];
  const float* D  = (const float*)d_in[4];
  const float* ld = (const float*)d_in[5];
  float* ws = (float*)d_ws;  // needs >= 81920 bytes

  s4_setup<<<65, NT, 0, stream>>>(u, A, B, C, ld, ws);
  s4_out<<<4096, 256, 0, stream>>>(ws, D, (float*)d_out);
}

// Round 6
// 190.376 us; speedup vs baseline: 1.3405x; 1.3405x over previous
//
#include <hip/hip_runtime.h>

// S4 -> causal conv. y[b,t] = d*u0[b,t] + sum_j k[j]*u0[b,t-j], k[j]=c^T Abar^j bbar.
// Abar = expm(dt*A): scale (theta=2) + Taylor-15 Paterson-Stockmeyer + squarings.
// bbar = dt*phi1(dtA)B: phi1 by PS on vectors + doubling through the squarings.
// k = CQ^T BR bilinear split; BR/CQ stored TRANSPOSED (BRT/CQT).
//
// Base = r4-verified 4-wave (256-thread) sync-sandwiched structure (76us).
// This revision (I$-bound + op-count theory):
//  (1) mm/mv/buildG are __noinline__ (one ~2KB body each, called repeatedly,
//      I$-resident) instead of ~150KB of once-through inlined straight-line code.
//  (2) BRT/CQT Krylov rows built by DOUBLING interleaved with the P/A power
//      chain (rows2:4=rows0:2*P2^T, 4:8=*P4^T, 8:16=*P8^T, 16:32=*P16^T,
//      32:64=*P32^T; same pattern as the already-verified 16:32/32:64
//      widenings) -- replaces 2x15 serial matvecs (-56 barriers).
//      Junk in not-yet-valid rows only propagates into rows overwritten by the
//      next doubling step.
//
// ws floats: [0,4096) k | [4096,20480) u0 | 20480 gX | 24832 gX2 | 29184 gX3
//            | 33536 gU0 | 37888 gU1 | 42240 gBRT | 46592 gCQT   (203776 B)

#define NT 256
#define MP 68
#define MB (64 * MP)

typedef __attribute__((ext_vector_type(8))) short v8s;
typedef __attribute__((ext_vector_type(4))) float v4f;

__device__ __forceinline__ unsigned short bf16r(float x) {
  union { float f; unsigned u; } v; v.f = x;
  unsigned r = v.u + 0x7fffu + ((v.u >> 16) & 1u);
  return (unsigned short)(r >> 16);
}
__device__ __forceinline__ float bf2f(unsigned short h) {
  union { unsigned u; float f; } v; v.u = ((unsigned)h) << 16;
  return v.f;
}
__device__ __forceinline__ void cvt4(const float4 f, ushort4* H, ushort4* L) {
  unsigned short h;
  h = bf16r(f.x); H->x = h; L->x = bf16r(f.x - bf2f(h));
  h = bf16r(f.y); H->y = h; L->y = bf16r(f.y - bf2f(h));
  h = bf16r(f.z); H->z = h; L->z = bf16r(f.z - bf2f(h));
  h = bf16r(f.w); H->w = h; L->w = bf16r(f.w - bf2f(h));
}

// FRAG layout (ushorts): A-hi @0, A-lo @4096, B-hi @8192, B-lo @12288.
// C[rowbase+i][colbase+j] = sum_k A[i][k]*B[k][j], pitches MP (Cd: cpitch).
// A rows at Ag (LDS or global). B: bT=0 -> B[k][n]=Bs[k*MP+n] (column staging);
// bT=1 -> B[k][n]=Bs[n*MP+k] (row staging of B^T). Tiles: R<nrt, Cc<nct.
// In-place safe for Cd==Ag==Bs (all staging reads complete before epilogue).
// Sync-sandwiched: entry + mid + end barriers (r2-verified discipline).
__device__ __attribute__((noinline)) void mm(const float* Ag, const float* Bs,
    int bT, float* Cd, int cpitch, float* Cd2,
    int nrt, int nct, int rowbase, unsigned short* FRAG) {
  const int t = threadIdx.x;
  __syncthreads();  // entry
  for (int s0 = 0; s0 < 512; s0 += 256) {
    const int s = s0 + t;
    const int l = s & 63, Tq = s >> 6;
    const int mrow = (Tq >> 1) * 16 + (l & 15);
    const int kk = (Tq & 1) * 32 + (l >> 4) * 8;
    const float* ap = Ag + mrow * MP + kk;
    const float4 f0 = *(const float4*)ap;
    const float4 f1 = *(const float4*)(ap + 4);
    ushort4 H0, L0, H1, L1;
    cvt4(f0, &H0, &L0); cvt4(f1, &H1, &L1);
    *(ushort4*)(FRAG + s * 8)            = H0;
    *(ushort4*)(FRAG + s * 8 + 4)        = H1;
    *(ushort4*)(FRAG + 4096 + s * 8)     = L0;
    *(ushort4*)(FRAG + 4096 + s * 8 + 4) = L1;
    float4 g0, g1;
    if (bT) {
      const float* bp = Bs + mrow * MP + kk;
      g0 = *(const float4*)bp;
      g1 = *(const float4*)(bp + 4);
    } else {
      g0.x = Bs[(kk + 0) * MP + mrow]; g0.y = Bs[(kk + 1) * MP + mrow];
      g0.z = Bs[(kk + 2) * MP + mrow]; g0.w = Bs[(kk + 3) * MP + mrow];
      g1.x = Bs[(kk + 4) * MP + mrow]; g1.y = Bs[(kk + 5) * MP + mrow];
      g1.z = Bs[(kk + 6) * MP + mrow]; g1.w = Bs[(kk + 7) * MP + mrow];
    }
    cvt4(g0, &H0, &L0); cvt4(g1, &H1, &L1);
    *(ushort4*)(FRAG + 8192 + s * 8)      = H0;
    *(ushort4*)(FRAG + 8192 + s * 8 + 4)  = H1;
    *(ushort4*)(FRAG + 12288 + s * 8)     = L0;
    *(ushort4*)(FRAG + 12288 + s * 8 + 4) = L1;
  }
  __syncthreads();  // mid
  {
    const int w = t >> 6, l = t & 63;
    if (w < nrt) {
      const v8s Ah0 = *(const v8s*)(FRAG + ((w * 2 + 0) * 64 + l) * 8);
      const v8s Ah1 = *(const v8s*)(FRAG + ((w * 2 + 1) * 64 + l) * 8);
      const v8s Al0 = *(const v8s*)(FRAG + 4096 + ((w * 2 + 0) * 64 + l) * 8);
      const v8s Al1 = *(const v8s*)(FRAG + 4096 + ((w * 2 + 1) * 64 + l) * 8);
      for (int Cc = 0; Cc < nct; ++Cc) {
        const v8s Bh0 = *(const v8s*)(FRAG + 8192 + ((Cc * 2 + 0) * 64 + l) * 8);
        const v8s Bh1 = *(const v8s*)(FRAG + 8192 + ((Cc * 2 + 1) * 64 + l) * 8);
        const v8s Bl0 = *(const v8s*)(FRAG + 12288 + ((Cc * 2 + 0) * 64 + l) * 8);
        const v8s Bl1 = *(const v8s*)(FRAG + 12288 + ((Cc * 2 + 1) * 64 + l) * 8);
        const v4f z = {0.f, 0.f, 0.f, 0.f};
        v4f a0 = __builtin_amdgcn_mfma_f32_16x16x32_bf16(Ah0, Bh0, z, 0, 0, 0);
        a0 = __builtin_amdgcn_mfma_f32_16x16x32_bf16(Ah1, Bh1, a0, 0, 0, 0);
        v4f a1 = __builtin_amdgcn_mfma_f32_16x16x32_bf16(Ah0, Bl0, z, 0, 0, 0);
        a1 = __builtin_amdgcn_mfma_f32_16x16x32_bf16(Ah1, Bl1, a1, 0, 0, 0);
        v4f a2 = __builtin_amdgcn_mfma_f32_16x16x32_bf16(Al0, Bh0, z, 0, 0, 0);
        a2 = __builtin_amdgcn_mfma_f32_16x16x32_bf16(Al1, Bh1, a2, 0, 0, 0);
        const int col = Cc * 16 + (l & 15);
        const int r0 = rowbase + w * 16 + (l >> 4) * 4;
        const float o0 = a0[0] + a1[0] + a2[0];
        const float o1 = a0[1] + a1[1] + a2[1];
        const float o2 = a0[2] + a1[2] + a2[2];
        const float o3 = a0[3] + a1[3] + a2[3];
        Cd[(r0 + 0) * cpitch + col] = o0;
        Cd[(r0 + 1) * cpitch + col] = o1;
        Cd[(r0 + 2) * cpitch + col] = o2;
        Cd[(r0 + 3) * cpitch + col] = o3;
        if (Cd2) {
          Cd2[(r0 + 0) * MP + col] = o0;
          Cd2[(r0 + 1) * MP + col] = o1;
          Cd2[(r0 + 2) * MP + col] = o2;
          Cd2[(r0 + 3) * MP + col] = o3;
        }
      }
    }
  }
  __syncthreads();  // end
}

// vout = M*vin (rows of M, pitch MP). 4 lanes per row, shfl-xor reduce.
// half: vout = 0.5*(M*vin + vin). out2: extra row store. Entry+end barriers.
__device__ __attribute__((noinline)) void mv64row(const float* M,
    const float* vin, float* vout, float* out2, int half) {
  const int t = threadIdx.x;
  __syncthreads();
  const int w = t >> 6, l = t & 63;
  const int row = w * 16 + (l >> 2), q = l & 3;
  const float* mp = M + row * MP + q * 16;
  const float* vp = vin + q * 16;
  float p = 0.f;
#pragma unroll
  for (int j = 0; j < 16; j += 4) {
    const float4 m = *(const float4*)(mp + j);
    p = fmaf(m.x, vp[j + 0], p);
    p = fmaf(m.y, vp[j + 1], p);
    p = fmaf(m.z, vp[j + 2], p);
    p = fmaf(m.w, vp[j + 3], p);
  }
  p += __shfl_xor(p, 1);
  p += __shfl_xor(p, 2);
  if (q == 0) {
    float s = half ? 0.5f * (p + vin[row]) : p;
    vout[row] = s;
    if (out2) out2[row] = s;
  }
  __syncthreads();
}

// vout = M^T*vin. 4 lanes per output col, shfl-xor reduce. Entry+end barriers.
__device__ __attribute__((noinline)) void mv64colT(const float* M,
    const float* vin, float* vout, float* out2) {
  const int t = threadIdx.x;
  __syncthreads();
  const int w = t >> 6, l = t & 63;
  const int col = w * 16 + (l >> 2), q = l & 3;
  float p = 0.f;
#pragma unroll
  for (int j = 0; j < 16; ++j)
    p = fmaf(M[(q * 16 + j) * MP + col], vin[q * 16 + j], p);
  p += __shfl_xor(p, 1);
  p += __shfl_xor(p, 2);
  if (q == 0) {
    vout[col] = p;
    if (out2) out2[col] = p;
  }
  __syncthreads();
}

// dst = c0*I + c1*X + c2*X2 + c3*X3 (+ addsrc). Pitch MP. Entry+end barriers.
__device__ __attribute__((noinline)) void buildG(float* dst, const float* X,
    const float* X2, const float* X3, float c0, float c1, float c2, float c3,
    const float* addsrc) {
  const int t = threadIdx.x;
  __syncthreads();
  const int r = t >> 2, cb = (t & 3) * 16;
#pragma unroll
  for (int j = 0; j < 16; j += 4) {
    const int c = cb + j;
    const int e = r * MP + c;
    const float4 x1 = *(const float4*)(X + e);
    const float4 x2 = *(const float4*)(X2 + e);
    const float4 x3 = *(const float4*)(X3 + e);
    float4 v;
    v.x = fmaf(c1, x1.x, fmaf(c2, x2.x, c3 * x3.x));
    v.y = fmaf(c1, x1.y, fmaf(c2, x2.y, c3 * x3.y));
    v.z = fmaf(c1, x1.z, fmaf(c2, x2.z, c3 * x3.z));
    v.w = fmaf(c1, x1.w, fmaf(c2, x2.w, c3 * x3.w));
    if (r == c + 0) v.x += c0;
    if (r == c + 1) v.y += c0;
    if (r == c + 2) v.z += c0;
    if (r == c + 3) v.w += c0;
    if (addsrc) {
      const float4 a = *(const float4*)(addsrc + e);
      v.x += a.x; v.y += a.y; v.z += a.z; v.w += a.w;
    }
    *(float4*)(dst + e) = v;
  }
  __syncthreads();
}

__global__ __launch_bounds__(NT) void s4_setup(const float* __restrict__ u,
    const float* __restrict__ A, const float* __restrict__ Bv,
    const float* __restrict__ Cv, const float* __restrict__ logdt,
    float* __restrict__ ws) {
  if (blockIdx.x > 0) {
    const int idx = (blockIdx.x - 1) * NT + threadIdx.x;  // 0..16383
    ws[4096 + idx] = u[(size_t)idx * 1024];
    return;
  }
  __shared__ __align__(16) float S0[MB];
  __shared__ __align__(16) unsigned short FRAG[16384];
  __shared__ float vB[64], v1[64], v2[64], v3[64], va[64], vb[64], vg[64];
  __shared__ int s_s;
  float* vscr = (float*)FRAG;  // overlay: only used by the 1-norm (pre-mm)

  const int t = threadIdx.x;
  float* kbuf = ws;
  float* gX   = ws + 20480;
  float* gX2  = ws + 24832;
  float* gX3  = ws + 29184;
  float* gU0  = ws + 33536;
  float* gU1  = ws + 37888;
  float* gBRT = ws + 42240;
  float* gCQT = ws + 46592;
  const float dt = expf(logdt[0]);

  const float invf[17] = {1.f, 1.f, 1.f / 2.f, 1.f / 6.f, 1.f / 24.f, 1.f / 120.f,
                          1.f / 720.f, 1.f / 5040.f, 1.f / 40320.f, 1.f / 362880.f,
                          1.f / 3628800.f, 1.f / 39916800.f, 1.f / 479001600.f,
                          1.f / 6.2270208e9f, 1.f / 8.71782912e10f,
                          1.f / 1.307674368e12f, 1.f / 2.0922789888e13f};

  // ---- 1-norm of dt*A -> s (theta = 2) ----
  {
    const int j = t & 63, w = t >> 6;
    float p = 0.f;
#pragma unroll
    for (int ii = 0; ii < 16; ++ii) p += fabsf(A[(w * 16 + ii) * 64 + j]);
    vscr[t] = p;
    __syncthreads();
    if (t < 64) {
      float cs = vscr[t] + vscr[64 + t] + vscr[128 + t] + vscr[192 + t];
      cs *= dt;
#pragma unroll
      for (int off = 32; off > 0; off >>= 1) cs = fmaxf(cs, __shfl_xor(cs, off));
      if (t == 0) {
        int s = 0;
        while (cs > 2.0f && s < 30) { cs *= 0.5f; ++s; }
        s_s = s;
      }
    }
    __syncthreads();
  }
  const int sq = s_s;
  const float scl = ldexpf(dt, -sq);

  // ---- X -> S0 and gX; vB ----
  {
    const int r = t >> 2, cb = (t & 3) * 16;
#pragma unroll
    for (int j = 0; j < 16; j += 4) {
      const float4 a4 = *(const float4*)(A + r * 64 + cb + j);
      float4 x;
      x.x = a4.x * scl; x.y = a4.y * scl; x.z = a4.z * scl; x.w = a4.w * scl;
      *(float4*)(S0 + r * MP + cb + j) = x;
      *(float4*)(gX + r * MP + cb + j) = x;
    }
    if (t < 64) vB[t] = Bv[t];
    __syncthreads();
  }

  // ---- powers: X2 (S0, +gX2), X3 (gX3), X4 (S0 in-place) ----
  mm(S0, S0, 0, S0, MP, gX2, 4, 4, 0, FRAG);        // X2
  mm(gX, S0, 0, gX3, MP, nullptr, 4, 4, 0, FRAG);   // X3 = X*X2
  mm(S0, S0, 0, S0, MP, nullptr, 4, 4, 0, FRAG);    // X4 = X2*X2

  // ---- phi1(X)*B via PS on vectors (deg-15, groups of 4 in X4) ----
  mv64row(gX,  vB, v1, nullptr, 0);
  mv64row(gX2, vB, v2, nullptr, 0);
  mv64row(gX3, vB, v3, nullptr, 0);
  if (t < 64)
    va[t] = invf[13] * vB[t] + invf[14] * v1[t] + invf[15] * v2[t] + invf[16] * v3[t];
  __syncthreads();
  mv64row(S0, va, vb, nullptr, 0);
  if (t < 64)
    va[t] = invf[9] * vB[t] + invf[10] * v1[t] + invf[11] * v2[t] + invf[12] * v3[t] + vb[t];
  __syncthreads();
  mv64row(S0, va, vb, nullptr, 0);
  if (t < 64)
    va[t] = invf[5] * vB[t] + invf[6] * v1[t] + invf[7] * v2[t] + invf[8] * v3[t] + vb[t];
  __syncthreads();
  mv64row(S0, va, vb, nullptr, 0);
  if (t < 64)
    vg[t] = invf[1] * vB[t] + invf[2] * v1[t] + invf[3] * v2[t] + invf[4] * v3[t] + vb[t];
  __syncthreads();

  // ---- e^X: Taylor-15 PS Horner (B-operand X4 in S0) ----
  buildG(gU0, gX, gX2, gX3, invf[12], invf[13], invf[14], invf[15], nullptr);
  mm(gU0, S0, 0, gU1, MP, nullptr, 4, 4, 0, FRAG);
  buildG(gU1, gX, gX2, gX3, invf[8], invf[9], invf[10], invf[11], gU1);
  mm(gU1, S0, 0, gU0, MP, nullptr, 4, 4, 0, FRAG);
  buildG(gU0, gX, gX2, gX3, invf[4], invf[5], invf[6], invf[7], gU0);
  mm(gU0, S0, 0, S0, MP, nullptr, 4, 4, 0, FRAG);   // -> S0 (over X4)
  buildG(S0, gX, gX2, gX3, invf[0], invf[1], invf[2], invf[3], S0);  // S0 = e^X

  // ---- squarings + phi1 doubling: g <- (F+I)g/2 (ping-pong vg/va) ----
  float* vcur = vg;
  float* vnxt = va;
  for (int it = 0; it < sq; ++it) {
    mv64row(S0, vcur, vnxt, nullptr, 1);  // vnxt = 0.5*(S0*vcur + vcur)
    { float* tmp = vcur; vcur = vnxt; vnxt = tmp; }
    mm(S0, S0, 0, S0, MP, nullptr, 4, 4, 0, FRAG);
  }
  // S0 = Abar, vcur = phi1 vector

  // ---- BRT seed: row0 = bbar, row1 = Abar*bbar ----
  if (t < 64) {
    const float bb = dt * vcur[t];
    v1[t] = bb;
    gBRT[t] = bb;
  }
  __syncthreads();
  mv64row(S0, v1, v2, gBRT + MP, 0);  // row1

  // ---- P-chain (in-place) + BRT Krylov doublings (rows m:2m = rows0:m*Pm^T)
  mm(S0, S0, 0, S0, MP, nullptr, 4, 4, 0, FRAG);       // P2
  mm(gBRT, S0, 1, gBRT, MP, nullptr, 1, 4, 2, FRAG);   // rows2:4   (junk 4:18 ok)
  mm(S0, S0, 0, S0, MP, nullptr, 4, 4, 0, FRAG);       // P4
  mm(gBRT, S0, 1, gBRT, MP, nullptr, 1, 4, 4, FRAG);   // rows4:8   (junk 8:20 ok)
  mm(S0, S0, 0, S0, MP, nullptr, 4, 4, 0, FRAG);       // P8
  mm(gBRT, S0, 1, gBRT, MP, nullptr, 1, 4, 8, FRAG);   // rows8:16  (junk 16:24 ok)
  mm(S0, S0, 0, S0, MP, nullptr, 4, 4, 0, FRAG);       // P16
  mm(gBRT, S0, 1, gBRT, MP, nullptr, 1, 4, 16, FRAG);  // rows16:32
  mm(S0, S0, 0, S0, MP, nullptr, 4, 4, 0, FRAG);       // P32
  mm(gBRT, S0, 1, gBRT, MP, nullptr, 2, 4, 32, FRAG);  // rows32:64
  mm(S0, S0, 0, S0, MP, nullptr, 4, 4, 0, FRAG);       // P64 = A64

  // ---- CQT seed: row0 = c, row1 = A64^T c (S0 = P64 here) ----
  if (t < 64) {
    const float cc = Cv[t];
    v1[t] = cc;
    gCQT[t] = cc;
  }
  __syncthreads();
  mv64colT(S0, v1, v2, gCQT + MP);  // row1

  // ---- A-chain (in-place) + CQT Krylov doublings (rows m:2m = rows0:m*A64^m)
  mm(S0, S0, 0, S0, MP, nullptr, 4, 4, 0, FRAG);       // A128
  mm(gCQT, S0, 0, gCQT, MP, nullptr, 1, 4, 2, FRAG);   // rows2:4
  mm(S0, S0, 0, S0, MP, nullptr, 4, 4, 0, FRAG);       // A256
  mm(gCQT, S0, 0, gCQT, MP, nullptr, 1, 4, 4, FRAG);   // rows4:8
  mm(S0, S0, 0, S0, MP, nullptr, 4, 4, 0, FRAG);       // A512
  mm(gCQT, S0, 0, gCQT, MP, nullptr, 1, 4, 8, FRAG);   // rows8:16
  mm(S0, S0, 0, S0, MP, nullptr, 4, 4, 0, FRAG);       // A1024
  mm(gCQT, S0, 0, gCQT, MP, nullptr, 1, 4, 16, FRAG);  // rows16:32
  mm(S0, S0, 0, S0, MP, nullptr, 4, 4, 0, FRAG);       // A2048
  mm(gCQT, S0, 0, gCQT, MP, nullptr, 2, 4, 32, FRAG);  // rows32:64

  // ---- k[q*64+r] = sum_i CQT[q][i]*BRT[r][i] ----
  mm(gCQT, gBRT, 1, kbuf, 64, nullptr, 4, 4, 0, FRAG);
}

// Fused conv + broadcast. 4096 blocks x 256 threads; block computes y[t0..t0+3]
// for one batch, then streams 4 rows x 1024 cols of broadcast stores.
// Conv: aligned sliding-window float4: y[t0+d] += sum_i k[b0+d-i]*u[s0+i],
// b0=t0-s0 (mult of 4); k via two aligned float4 (k1 zeroed at b0==0).
__global__ __launch_bounds__(256) void s4_out(const float* __restrict__ ws,
                                              const float* __restrict__ Dp,
                                              float* __restrict__ out) {
  const int bid = blockIdx.x;
  const int b = bid >> 10;
  const int t0 = (bid & 1023) << 2;
  const float* kb = ws;
  const float* ub = ws + 4096 + (b << 12);
  const int tid = threadIdx.x;

  float a0 = 0.f, a1 = 0.f, a2 = 0.f, a3 = 0.f;
  for (int s0 = tid << 2; s0 <= t0; s0 += 1024) {
    const float4 uv = *(const float4*)(ub + s0);
    const int b0 = t0 - s0;
    const float4 k0 = *(const float4*)(kb + b0);
    float4 k1 = make_float4(0.f, 0.f, 0.f, 0.f);
    if (b0 >= 4) k1 = *(const float4*)(kb + b0 - 4);
    a0 = fmaf(k0.x, uv.x, a0);
    a0 = fmaf(k1.w, uv.y, a0);
    a0 = fmaf(k1.z, uv.z, a0);
    a0 = fmaf(k1.y, uv.w, a0);
    a1 = fmaf(k0.y, uv.x, a1);
    a1 = fmaf(k0.x, uv.y, a1);
    a1 = fmaf(k1.w, uv.z, a1);
    a1 = fmaf(k1.z, uv.w, a1);
    a2 = fmaf(k0.z, uv.x, a2);
    a2 = fmaf(k0.y, uv.y, a2);
    a2 = fmaf(k0.x, uv.z, a2);
    a2 = fmaf(k1.w, uv.w, a2);
    a3 = fmaf(k0.w, uv.x, a3);
    a3 = fmaf(k0.z, uv.y, a3);
    a3 = fmaf(k0.y, uv.z, a3);
    a3 = fmaf(k0.x, uv.w, a3);
  }
#pragma unroll
  for (int off = 32; off > 0; off >>= 1) {
    a0 += __shfl_xor(a0, off);
    a1 += __shfl_xor(a1, off);
    a2 += __shfl_xor(a2, off);
    a3 += __shfl_xor(a3, off);
  }
  __shared__ float red[4][4];
  __shared__ float sy[4];
  if ((tid & 63) == 0) {
    const int w = tid >> 6;
    red[0][w] = a0; red[1][w] = a1; red[2][w] = a2; red[3][w] = a3;
  }
  __syncthreads();
  if (tid < 4)
    sy[tid] = red[tid][0] + red[tid][1] + red[tid][2] + red[tid][3] +
              Dp[0] * ub[t0 + tid];
  __syncthreads();
  const int row = tid >> 6, lx = tid & 63;
  const float y = sy[row];
  const v4f y4 = {y, y, y, y};
  v4f* dst = (v4f*)(out + ((size_t)(b << 12) + t0 + row) * 1024);
  __builtin_nontemporal_store(y4, dst + lx);
  __builtin_nontemporal_store(y4, dst + lx + 64);
  __builtin_nontemporal_store(y4, dst + lx + 128);
  __builtin_nontemporal_store(y4, dst + lx + 192);
}

extern "C" void kernel_launch(void* const* d_in, const int* in_sizes, int n_in,
                              void* d_out, int out_size, void* d_ws, size_t ws_size,
                              hipStream_t stream) {
  const float* u  = (const float*)d_in[0];
  const float* A  = (const float*)d_in[1];
  const float* B  = (const float*)d_in[2];
  const float* C  = (const float*)d_in[3];
  const float* D  = (const float*)d_in[4];
  const float* ld = (const float*)d_in[5];
  float* ws = (float*)d_ws;  // needs >= 203776 bytes

  s4_setup<<<65, NT, 0, stream>>>(u, A, B, C, ld, ws);
  s4_out<<<4096, 256, 0, stream>>>(ws, D, (float*)d_out);
}

// Round 7
// 177.769 us; speedup vs baseline: 1.4356x; 1.0709x over previous
//
#include <hip/hip_runtime.h>

// S4 -> causal conv. y[b,t] = d*u0[b,t] + sum_j k[j]*u0[b,t-j], k[j]=c^T Abar^j bbar.
// Abar = expm(dt*A): scale (theta=2) + Taylor-15 Paterson-Stockmeyer + squarings.
// bbar = dt*phi1(dtA)B: phi1 by PS on vectors + doubling through the squarings.
// k = CQ^T BR bilinear split; BR/CQ stored TRANSPOSED (BRT/CQT).
//
// Base = r4-verified 4-wave sync-sandwiched structure (76us, 27mm+42mv).
// SINGLE CHANGE vs r4: all 6 matrix slots in LDS (S0,SX,SX2,SX3,SU0,SU1;
// BRT/CQT reuse SU0/SU1 after Horner frees them; 137KB total). Theory: the
// 2.3us/mm cost (r4/r6 regression: 27mm+42mv=76 vs 33mm+12mv=79) is global-ws
// operand gathers + store-ack stalls at every barrier's vmcnt(0) drain. With
// the chain all-LDS, barriers drain only lgkmcnt and staging is LDS-latency.
//
// ws floats: [0,4096) k | [4096,20480) u0   (81920 B)

#define NT 256
#define MP 68
#define MB (64 * MP)

typedef __attribute__((ext_vector_type(8))) short v8s;
typedef __attribute__((ext_vector_type(4))) float v4f;

__device__ __forceinline__ unsigned short bf16r(float x) {
  union { float f; unsigned u; } v; v.f = x;
  unsigned r = v.u + 0x7fffu + ((v.u >> 16) & 1u);
  return (unsigned short)(r >> 16);
}
__device__ __forceinline__ float bf2f(unsigned short h) {
  union { unsigned u; float f; } v; v.u = ((unsigned)h) << 16;
  return v.f;
}
__device__ __forceinline__ void cvt4(const float4 f, ushort4* H, ushort4* L) {
  unsigned short h;
  h = bf16r(f.x); H->x = h; L->x = bf16r(f.x - bf2f(h));
  h = bf16r(f.y); H->y = h; L->y = bf16r(f.y - bf2f(h));
  h = bf16r(f.z); H->z = h; L->z = bf16r(f.z - bf2f(h));
  h = bf16r(f.w); H->w = h; L->w = bf16r(f.w - bf2f(h));
}

// FRAG layout (ushorts): A-hi @0, A-lo @4096, B-hi @8192, B-lo @12288.
// C[rowbase+i][colbase+j] = sum_k A[i][k]*B[k][j], pitches MP (Cd: cpitch).
// A rows at Ag. B: bT=0 -> B[k][n]=Bs[k*MP+n]; bT=1 -> B[k][n]=Bs[n*MP+k].
// In-place safe for Cd==Ag==Bs. Sync-sandwiched (entry+mid+end barriers).
__device__ void mm(const float* Ag, const float* Bs, int bT,
                   float* Cd, int cpitch, float* Cd2,
                   int nrt, int nct, int rowbase, int colbase,
                   unsigned short* FRAG) {
  const int t = threadIdx.x;
  __syncthreads();  // entry
  for (int s0 = 0; s0 < 512; s0 += 256) {
    const int s = s0 + t;
    const int l = s & 63, Tq = s >> 6;
    const int mrow = (Tq >> 1) * 16 + (l & 15);
    const int kk = (Tq & 1) * 32 + (l >> 4) * 8;
    const float* ap = Ag + mrow * MP + kk;
    const float4 f0 = *(const float4*)ap;
    const float4 f1 = *(const float4*)(ap + 4);
    ushort4 H0, L0, H1, L1;
    cvt4(f0, &H0, &L0); cvt4(f1, &H1, &L1);
    *(ushort4*)(FRAG + s * 8)            = H0;
    *(ushort4*)(FRAG + s * 8 + 4)        = H1;
    *(ushort4*)(FRAG + 4096 + s * 8)     = L0;
    *(ushort4*)(FRAG + 4096 + s * 8 + 4) = L1;
    float4 g0, g1;
    if (bT) {
      const float* bp = Bs + mrow * MP + kk;
      g0 = *(const float4*)bp;
      g1 = *(const float4*)(bp + 4);
    } else {
      g0.x = Bs[(kk + 0) * MP + mrow]; g0.y = Bs[(kk + 1) * MP + mrow];
      g0.z = Bs[(kk + 2) * MP + mrow]; g0.w = Bs[(kk + 3) * MP + mrow];
      g1.x = Bs[(kk + 4) * MP + mrow]; g1.y = Bs[(kk + 5) * MP + mrow];
      g1.z = Bs[(kk + 6) * MP + mrow]; g1.w = Bs[(kk + 7) * MP + mrow];
    }
    cvt4(g0, &H0, &L0); cvt4(g1, &H1, &L1);
    *(ushort4*)(FRAG + 8192 + s * 8)      = H0;
    *(ushort4*)(FRAG + 8192 + s * 8 + 4)  = H1;
    *(ushort4*)(FRAG + 12288 + s * 8)     = L0;
    *(ushort4*)(FRAG + 12288 + s * 8 + 4) = L1;
  }
  __syncthreads();  // mid
  {
    const int w = t >> 6, l = t & 63;
    if (w < nrt) {
      const v8s Ah0 = *(const v8s*)(FRAG + ((w * 2 + 0) * 64 + l) * 8);
      const v8s Ah1 = *(const v8s*)(FRAG + ((w * 2 + 1) * 64 + l) * 8);
      const v8s Al0 = *(const v8s*)(FRAG + 4096 + ((w * 2 + 0) * 64 + l) * 8);
      const v8s Al1 = *(const v8s*)(FRAG + 4096 + ((w * 2 + 1) * 64 + l) * 8);
      for (int Cc = 0; Cc < nct; ++Cc) {
        const v8s Bh0 = *(const v8s*)(FRAG + 8192 + ((Cc * 2 + 0) * 64 + l) * 8);
        const v8s Bh1 = *(const v8s*)(FRAG + 8192 + ((Cc * 2 + 1) * 64 + l) * 8);
        const v8s Bl0 = *(const v8s*)(FRAG + 12288 + ((Cc * 2 + 0) * 64 + l) * 8);
        const v8s Bl1 = *(const v8s*)(FRAG + 12288 + ((Cc * 2 + 1) * 64 + l) * 8);
        const v4f z = {0.f, 0.f, 0.f, 0.f};
        v4f a0 = __builtin_amdgcn_mfma_f32_16x16x32_bf16(Ah0, Bh0, z, 0, 0, 0);
        a0 = __builtin_amdgcn_mfma_f32_16x16x32_bf16(Ah1, Bh1, a0, 0, 0, 0);
        v4f a1 = __builtin_amdgcn_mfma_f32_16x16x32_bf16(Ah0, Bl0, z, 0, 0, 0);
        a1 = __builtin_amdgcn_mfma_f32_16x16x32_bf16(Ah1, Bl1, a1, 0, 0, 0);
        v4f a2 = __builtin_amdgcn_mfma_f32_16x16x32_bf16(Al0, Bh0, z, 0, 0, 0);
        a2 = __builtin_amdgcn_mfma_f32_16x16x32_bf16(Al1, Bh1, a2, 0, 0, 0);
        const int col = colbase + Cc * 16 + (l & 15);
        const int r0 = rowbase + w * 16 + (l >> 4) * 4;
        const float o0 = a0[0] + a1[0] + a2[0];
        const float o1 = a0[1] + a1[1] + a2[1];
        const float o2 = a0[2] + a1[2] + a2[2];
        const float o3 = a0[3] + a1[3] + a2[3];
        Cd[(r0 + 0) * cpitch + col] = o0;
        Cd[(r0 + 1) * cpitch + col] = o1;
        Cd[(r0 + 2) * cpitch + col] = o2;
        Cd[(r0 + 3) * cpitch + col] = o3;
        if (Cd2) {
          Cd2[(r0 + 0) * MP + col] = o0;
          Cd2[(r0 + 1) * MP + col] = o1;
          Cd2[(r0 + 2) * MP + col] = o2;
          Cd2[(r0 + 3) * MP + col] = o3;
        }
      }
    }
  }
  __syncthreads();  // end
}

// vout = M*vin (rows of M, pitch MP). 4 lanes per row, shfl-xor reduce.
// half: vout = 0.5*(M*vin + vin). out2: extra row store. Entry+end barriers.
__device__ __forceinline__ void mv64row(const float* M, const float* vin,
                                        float* vout, float* out2, int half) {
  const int t = threadIdx.x;
  __syncthreads();
  const int w = t >> 6, l = t & 63;
  const int row = w * 16 + (l >> 2), q = l & 3;
  const float* mp = M + row * MP + q * 16;
  const float* vp = vin + q * 16;
  float p = 0.f;
#pragma unroll
  for (int j = 0; j < 16; j += 4) {
    const float4 m = *(const float4*)(mp + j);
    p = fmaf(m.x, vp[j + 0], p);
    p = fmaf(m.y, vp[j + 1], p);
    p = fmaf(m.z, vp[j + 2], p);
    p = fmaf(m.w, vp[j + 3], p);
  }
  p += __shfl_xor(p, 1);
  p += __shfl_xor(p, 2);
  if (q == 0) {
    float s = half ? 0.5f * (p + vin[row]) : p;
    vout[row] = s;
    if (out2) out2[row] = s;
  }
  __syncthreads();
}

// vout = M^T*vin. 4 lanes per output col, shfl-xor reduce. Entry+end barriers.
__device__ __forceinline__ void mv64colT(const float* M, const float* vin,
                                         float* vout, float* out2) {
  const int t = threadIdx.x;
  __syncthreads();
  const int w = t >> 6, l = t & 63;
  const int col = w * 16 + (l >> 2), q = l & 3;
  float p = 0.f;
#pragma unroll
  for (int j = 0; j < 16; ++j)
    p = fmaf(M[(q * 16 + j) * MP + col], vin[q * 16 + j], p);
  p += __shfl_xor(p, 1);
  p += __shfl_xor(p, 2);
  if (q == 0) {
    vout[col] = p;
    if (out2) out2[col] = p;
  }
  __syncthreads();
}

// dst = c0*I + c1*X + c2*X2 + c3*X3 (+ addsrc). Pitch MP. Entry+end barriers.
__device__ void buildG(float* dst, const float* X, const float* X2, const float* X3,
                       float c0, float c1, float c2, float c3, const float* addsrc) {
  const int t = threadIdx.x;
  __syncthreads();
  const int r = t >> 2, cb = (t & 3) * 16;
#pragma unroll
  for (int j = 0; j < 16; j += 4) {
    const int c = cb + j;
    const int e = r * MP + c;
    const float4 x1 = *(const float4*)(X + e);
    const float4 x2 = *(const float4*)(X2 + e);
    const float4 x3 = *(const float4*)(X3 + e);
    float4 v;
    v.x = fmaf(c1, x1.x, fmaf(c2, x2.x, c3 * x3.x));
    v.y = fmaf(c1, x1.y, fmaf(c2, x2.y, c3 * x3.y));
    v.z = fmaf(c1, x1.z, fmaf(c2, x2.z, c3 * x3.z));
    v.w = fmaf(c1, x1.w, fmaf(c2, x2.w, c3 * x3.w));
    if (r == c + 0) v.x += c0;
    if (r == c + 1) v.y += c0;
    if (r == c + 2) v.z += c0;
    if (r == c + 3) v.w += c0;
    if (addsrc) {
      const float4 a = *(const float4*)(addsrc + e);
      v.x += a.x; v.y += a.y; v.z += a.z; v.w += a.w;
    }
    *(float4*)(dst + e) = v;
  }
  __syncthreads();
}

__global__ __launch_bounds__(NT) void s4_setup(const float* __restrict__ u,
    const float* __restrict__ A, const float* __restrict__ Bv,
    const float* __restrict__ Cv, const float* __restrict__ logdt,
    float* __restrict__ ws) {
  if (blockIdx.x > 0) {
    const int idx = (blockIdx.x - 1) * NT + threadIdx.x;  // 0..16383
    ws[4096 + idx] = u[(size_t)idx * 1024];
    return;
  }
  // All matrix slots in LDS: 6 x 17408B + FRAG 32KB + vecs ~ 139KB (<160KB).
  __shared__ __align__(16) float S0[MB];
  __shared__ __align__(16) float SX[MB];
  __shared__ __align__(16) float SX2[MB];
  __shared__ __align__(16) float SX3[MB];
  __shared__ __align__(16) float SU0[MB];
  __shared__ __align__(16) float SU1[MB];
  __shared__ __align__(16) unsigned short FRAG[16384];
  __shared__ float vB[64], v1[64], v2[64], v3[64], va[64], vb[64], vg[64];
  __shared__ int s_s;
  float* vscr = (float*)FRAG;  // overlay: only used by the 1-norm (pre-mm)

  const int t = threadIdx.x;
  float* kbuf = ws;
  float* SBRT = SU0;  // reused after Horner frees U0
  float* SCQT = SU1;  // reused after Horner frees U1
  const float dt = expf(logdt[0]);

  const float invf[17] = {1.f, 1.f, 1.f / 2.f, 1.f / 6.f, 1.f / 24.f, 1.f / 120.f,
                          1.f / 720.f, 1.f / 5040.f, 1.f / 40320.f, 1.f / 362880.f,
                          1.f / 3628800.f, 1.f / 39916800.f, 1.f / 479001600.f,
                          1.f / 6.2270208e9f, 1.f / 8.71782912e10f,
                          1.f / 1.307674368e12f, 1.f / 2.0922789888e13f};

  // ---- 1-norm of dt*A -> s (theta = 2) ----
  {
    const int j = t & 63, w = t >> 6;
    float p = 0.f;
#pragma unroll
    for (int ii = 0; ii < 16; ++ii) p += fabsf(A[(w * 16 + ii) * 64 + j]);
    vscr[t] = p;
    __syncthreads();
    if (t < 64) {
      float cs = vscr[t] + vscr[64 + t] + vscr[128 + t] + vscr[192 + t];
      cs *= dt;
#pragma unroll
      for (int off = 32; off > 0; off >>= 1) cs = fmaxf(cs, __shfl_xor(cs, off));
      if (t == 0) {
        int s = 0;
        while (cs > 2.0f && s < 30) { cs *= 0.5f; ++s; }
        s_s = s;
      }
    }
    __syncthreads();
  }
  const int sq = s_s;
  const float scl = ldexpf(dt, -sq);

  // ---- X -> S0 and SX; vB ----
  {
    const int r = t >> 2, cb = (t & 3) * 16;
#pragma unroll
    for (int j = 0; j < 16; j += 4) {
      const float4 a4 = *(const float4*)(A + r * 64 + cb + j);
      float4 x;
      x.x = a4.x * scl; x.y = a4.y * scl; x.z = a4.z * scl; x.w = a4.w * scl;
      *(float4*)(S0 + r * MP + cb + j) = x;
      *(float4*)(SX + r * MP + cb + j) = x;
    }
    if (t < 64) vB[t] = Bv[t];
    __syncthreads();
  }

  // ---- powers: X2 (S0, +SX2), X3 (SX3), X4 (S0 in-place) ----
  mm(S0, S0, 0, S0, MP, SX2, 4, 4, 0, 0, FRAG);        // X2
  mm(SX, S0, 0, SX3, MP, nullptr, 4, 4, 0, 0, FRAG);   // X3 = X*X2
  mm(S0, S0, 0, S0, MP, nullptr, 4, 4, 0, 0, FRAG);    // X4 = X2*X2

  // ---- phi1(X)*B via PS on vectors (deg-15, groups of 4 in X4) ----
  mv64row(SX,  vB, v1, nullptr, 0);
  mv64row(SX2, vB, v2, nullptr, 0);
  mv64row(SX3, vB, v3, nullptr, 0);
  if (t < 64)
    va[t] = invf[13] * vB[t] + invf[14] * v1[t] + invf[15] * v2[t] + invf[16] * v3[t];
  __syncthreads();
  mv64row(S0, va, vb, nullptr, 0);
  if (t < 64)
    va[t] = invf[9] * vB[t] + invf[10] * v1[t] + invf[11] * v2[t] + invf[12] * v3[t] + vb[t];
  __syncthreads();
  mv64row(S0, va, vb, nullptr, 0);
  if (t < 64)
    va[t] = invf[5] * vB[t] + invf[6] * v1[t] + invf[7] * v2[t] + invf[8] * v3[t] + vb[t];
  __syncthreads();
  mv64row(S0, va, vb, nullptr, 0);
  if (t < 64)
    vg[t] = invf[1] * vB[t] + invf[2] * v1[t] + invf[3] * v2[t] + invf[4] * v3[t] + vb[t];
  __syncthreads();

  // ---- e^X: Taylor-15 PS Horner (B-operand X4 in S0) ----
  buildG(SU0, SX, SX2, SX3, invf[12], invf[13], invf[14], invf[15], nullptr);
  mm(SU0, S0, 0, SU1, MP, nullptr, 4, 4, 0, 0, FRAG);
  buildG(SU1, SX, SX2, SX3, invf[8], invf[9], invf[10], invf[11], SU1);
  mm(SU1, S0, 0, SU0, MP, nullptr, 4, 4, 0, 0, FRAG);
  buildG(SU0, SX, SX2, SX3, invf[4], invf[5], invf[6], invf[7], SU0);
  mm(SU0, S0, 0, S0, MP, nullptr, 4, 4, 0, 0, FRAG);   // -> S0 (over X4)
  buildG(S0, SX, SX2, SX3, invf[0], invf[1], invf[2], invf[3], S0);  // S0 = e^X

  // ---- squarings + phi1 doubling: g <- (F+I)g/2 (ping-pong vg/va) ----
  float* vcur = vg;
  float* vnxt = va;
  for (int it = 0; it < sq; ++it) {
    mv64row(S0, vcur, vnxt, nullptr, 1);  // vnxt = 0.5*(S0*vcur + vcur)
    { float* tmp = vcur; vcur = vnxt; vnxt = tmp; }
    mm(S0, S0, 0, S0, MP, nullptr, 4, 4, 0, 0, FRAG);
  }
  // S0 = Abar, vcur = phi1 vector

  // ---- BRT rows 0..15: bbar then Abar^r bbar (row store folded into mv) ----
  if (t < 64) {
    const float bb = dt * vcur[t];
    v1[t] = bb;
    SBRT[t] = bb;
  }
  __syncthreads();
  {
    float* vc = v1; float* vn = v2;
    for (int r = 1; r < 16; ++r) {
      mv64row(S0, vc, vn, SBRT + r * MP, 0);
      float* tmp = vc; vc = vn; vn = tmp;
    }
  }

  // ---- P-chain (in-place) + BRT widenings ----
  mm(S0, S0, 0, S0, MP, nullptr, 4, 4, 0, 0, FRAG);        // P2
  mm(S0, S0, 0, S0, MP, nullptr, 4, 4, 0, 0, FRAG);        // P4
  mm(S0, S0, 0, S0, MP, nullptr, 4, 4, 0, 0, FRAG);        // P8
  mm(S0, S0, 0, S0, MP, nullptr, 4, 4, 0, 0, FRAG);        // P16
  mm(SBRT, S0, 1, SBRT, MP, nullptr, 1, 4, 16, 0, FRAG);   // rows16:32 = BRT0:16*P16^T
  mm(S0, S0, 0, S0, MP, nullptr, 4, 4, 0, 0, FRAG);        // P32
  mm(SBRT, S0, 1, SBRT, MP, nullptr, 2, 4, 32, 0, FRAG);   // rows32:64
  mm(S0, S0, 0, S0, MP, nullptr, 4, 4, 0, 0, FRAG);        // P64

  // ---- CQT rows 0..15: c then (P64^T)^q c (row store folded into mv) ----
  if (t < 64) {
    const float cc = Cv[t];
    v1[t] = cc;
    SCQT[t] = cc;
  }
  __syncthreads();
  {
    float* vc = v1; float* vn = v2;
    for (int qx = 1; qx < 16; ++qx) {
      mv64colT(S0, vc, vn, SCQT + qx * MP);
      float* tmp = vc; vc = vn; vn = tmp;
    }
  }

  // ---- A-chain (in-place) + CQT widenings ----
  mm(S0, S0, 0, S0, MP, nullptr, 4, 4, 0, 0, FRAG);        // A128
  mm(S0, S0, 0, S0, MP, nullptr, 4, 4, 0, 0, FRAG);        // A256
  mm(S0, S0, 0, S0, MP, nullptr, 4, 4, 0, 0, FRAG);        // A512
  mm(S0, S0, 0, S0, MP, nullptr, 4, 4, 0, 0, FRAG);        // A1024
  mm(SCQT, S0, 0, SCQT, MP, nullptr, 1, 4, 16, 0, FRAG);   // rows16:32 = CQT0:16*A1024
  mm(S0, S0, 0, S0, MP, nullptr, 4, 4, 0, 0, FRAG);        // A2048
  mm(SCQT, S0, 0, SCQT, MP, nullptr, 2, 4, 32, 0, FRAG);   // rows32:64

  // ---- k[q*64+r] = sum_i CQT[q][i]*BRT[r][i] (only global write) ----
  mm(SCQT, SBRT, 1, kbuf, 64, nullptr, 4, 4, 0, 0, FRAG);
}

// Fused conv + broadcast. 4096 blocks x 256 threads; block computes y[t0..t0+3]
// for one batch, then streams 4 rows x 1024 cols of broadcast stores.
// Conv: aligned sliding-window float4: y[t0+d] += sum_i k[b0+d-i]*u[s0+i],
// b0=t0-s0 (mult of 4); k via two aligned float4 (k1 zeroed at b0==0).
__global__ __launch_bounds__(256) void s4_out(const float* __restrict__ ws,
                                              const float* __restrict__ Dp,
                                              float* __restrict__ out) {
  const int bid = blockIdx.x;
  const int b = bid >> 10;
  const int t0 = (bid & 1023) << 2;
  const float* kb = ws;
  const float* ub = ws + 4096 + (b << 12);
  const int tid = threadIdx.x;

  float a0 = 0.f, a1 = 0.f, a2 = 0.f, a3 = 0.f;
  for (int s0 = tid << 2; s0 <= t0; s0 += 1024) {
    const float4 uv = *(const float4*)(ub + s0);
    const int b0 = t0 - s0;
    const float4 k0 = *(const float4*)(kb + b0);
    float4 k1 = make_float4(0.f, 0.f, 0.f, 0.f);
    if (b0 >= 4) k1 = *(const float4*)(kb + b0 - 4);
    a0 = fmaf(k0.x, uv.x, a0);
    a0 = fmaf(k1.w, uv.y, a0);
    a0 = fmaf(k1.z, uv.z, a0);
    a0 = fmaf(k1.y, uv.w, a0);
    a1 = fmaf(k0.y, uv.x, a1);
    a1 = fmaf(k0.x, uv.y, a1);
    a1 = fmaf(k1.w, uv.z, a1);
    a1 = fmaf(k1.z, uv.w, a1);
    a2 = fmaf(k0.z, uv.x, a2);
    a2 = fmaf(k0.y, uv.y, a2);
    a2 = fmaf(k0.x, uv.z, a2);
    a2 = fmaf(k1.w, uv.w, a2);
    a3 = fmaf(k0.w, uv.x, a3);
    a3 = fmaf(k0.z, uv.y, a3);
    a3 = fmaf(k0.y, uv.z, a3);
    a3 = fmaf(k0.x, uv.w, a3);
  }
#pragma unroll
  for (int off = 32; off > 0; off >>= 1) {
    a0 += __shfl_xor(a0, off);
    a1 += __shfl_xor(a1, off);
    a2 += __shfl_xor(a2, off);
    a3 += __shfl_xor(a3, off);
  }
  __shared__ float red[4][4];
  __shared__ float sy[4];
  if ((tid & 63) == 0) {
    const int w = tid >> 6;
    red[0][w] = a0; red[1][w] = a1; red[2][w] = a2; red[3][w] = a3;
  }
  __syncthreads();
  if (tid < 4)
    sy[tid] = red[tid][0] + red[tid][1] + red[tid][2] + red[tid][3] +
              Dp[0] * ub[t0 + tid];
  __syncthreads();
  const int row = tid >> 6, lx = tid & 63;
  const float y = sy[row];
  const v4f y4 = {y, y, y, y};
  v4f* dst = (v4f*)(out + ((size_t)(b << 12) + t0 + row) * 1024);
  __builtin_nontemporal_store(y4, dst + lx);
  __builtin_nontemporal_store(y4, dst + lx + 64);
  __builtin_nontemporal_store(y4, dst + lx + 128);
  __builtin_nontemporal_store(y4, dst + lx + 192);
}

extern "C" void kernel_launch(void* const* d_in, const int* in_sizes, int n_in,
                              void* d_out, int out_size, void* d_ws, size_t ws_size,
                              hipStream_t stream) {
  const float* u  = (const float*)d_in[0];
  const float* A  = (const float*)d_in[1];
  const float* B  = (const float*)d_in[2];
  const float* C  = (const float*)d_in[3];
  const float* D  = (const float*)d_in[4];
  const float* ld = (const float*)d_in[5];
  float* ws = (float*)d_ws;  // needs >= 81920 bytes

  s4_setup<<<65, NT, 0, stream>>>(u, A, B, C, ld, ws);
  s4_out<<<4096, 256, 0, stream>>>(ws, D, (float*)d_out);
}

// Round 8
// 170.784 us; speedup vs baseline: 1.4943x; 1.0409x over previous
//
#include <hip/hip_runtime.h>

// S4 -> causal conv. y[b,t] = d*u0[b,t] + sum_j k[j]*u0[b,t-j], k[j]=c^T Abar^j bbar.
// Abar = expm(dt*A): scale (theta=2) + Taylor-15 Paterson-Stockmeyer + squarings.
// bbar = dt*phi1(dtA)B: phi1 by PS on vectors + doubling through the squarings.
// k = CQ^T BR bilinear split; BR/CQ stored TRANSPOSED (BRT/CQT).
//
// Base = r7-verified all-LDS 4-wave sync-sandwiched structure (65.4us).
// r8 changes (LDS-BW + unroll theory; mappings/barriers unchanged):
//  (1) A-operand loaded DIRECTLY from f32 LDS in the compute phase and cvt'd
//      in registers (r5-verified mm1w pattern) -> A removed from staging
//      (-32KB LDS traffic/mm, staging halves). FRAG now holds only B (16KB).
//  (2) mm templatized <NRT,NCT,BT,FA,FC>: compile-time trip counts, full
//      unroll, B-frag loads hoisted (was runtime nct -> serialized iters).
//  (3) Horner's 4 buildG fused into mm: FA builds A = c0I+c1X+c2X2+c3X3 on
//      the fly; FC adds the next G in the epilogue. phi-combines fused into
//      mv64row_phi. -7 ops.
//
// ws floats: [0,4096) k | [4096,20480) u0   (81920 B)

#define NT 256
#define MP 68
#define MB (64 * MP)

typedef __attribute__((ext_vector_type(8))) short v8s;
typedef __attribute__((ext_vector_type(4))) float v4f;

__device__ __forceinline__ unsigned short bf16r(float x) {
  union { float f; unsigned u; } v; v.f = x;
  unsigned r = v.u + 0x7fffu + ((v.u >> 16) & 1u);
  return (unsigned short)(r >> 16);
}
__device__ __forceinline__ float bf2f(unsigned short h) {
  union { unsigned u; float f; } v; v.u = ((unsigned)h) << 16;
  return v.f;
}
__device__ __forceinline__ void cvt4(const float4 f, ushort4* H, ushort4* L) {
  unsigned short h;
  h = bf16r(f.x); H->x = h; L->x = bf16r(f.x - bf2f(h));
  h = bf16r(f.y); H->y = h; L->y = bf16r(f.y - bf2f(h));
  h = bf16r(f.z); H->z = h; L->z = bf16r(f.z - bf2f(h));
  h = bf16r(f.w); H->w = h; L->w = bf16r(f.w - bf2f(h));
}
__device__ __forceinline__ void cvt8(const float4 f0, const float4 f1,
                                     v8s* H, v8s* L) {
  union { v8s v; ushort4 u[2]; } Hu, Lu;
  cvt4(f0, &Hu.u[0], &Lu.u[0]);
  cvt4(f1, &Hu.u[1], &Lu.u[1]);
  *H = Hu.v; *L = Lu.v;
}

// C[rowbase+i][j] = sum_k A[i][k]*B[k][j], i < 16*NRT, j < 16*NCT.
// B: BT=0 -> B[k][n]=Bs[k*MP+n]; BT=1 -> B[k][n]=Bs[n*MP+k]. Staged to FRAG
// (bf16 hi @0, lo @4096 ushorts) with the r2-verified slot map.
// A: rows w*16.. read directly from Ag (f32, pitch MP) in compute phase;
//    FA!=0: A = cA.x*I + cA.y*GX + cA.z*GX2 + cA.w*GX3 instead of Ag.
// FC!=0: epilogue adds cC.x*I + cC.y*GX + cC.z*GX2 + cC.w*GX3 (rowbase==0).
// In-place safe (wave w reads A rows w*16..+15 before storing same rows;
// cross-wave rows disjoint; B fully staged before mid barrier).
template<int NRT, int NCT, int BT, int FA, int FC>
__device__ void mm(const float* Ag, const float* Bs, float* Cd, int cpitch,
                   float* Cd2, int rowbase,
                   const float* GX, const float* GX2, const float* GX3,
                   float4 cA, float4 cC, unsigned short* FRAG) {
  const int t = threadIdx.x;
  __syncthreads();  // entry
#pragma unroll
  for (int s0 = 0; s0 < 512; s0 += 256) {
    const int s = s0 + t;
    const int l = s & 63, Tq = s >> 6;              // Tq = Cc*2 + half
    const int col = (Tq >> 1) * 16 + (l & 15);
    const int kk = (Tq & 1) * 32 + (l >> 4) * 8;
    float4 g0, g1;
    if (BT) {
      const float* bp = Bs + col * MP + kk;
      g0 = *(const float4*)bp;
      g1 = *(const float4*)(bp + 4);
    } else {
      g0.x = Bs[(kk + 0) * MP + col]; g0.y = Bs[(kk + 1) * MP + col];
      g0.z = Bs[(kk + 2) * MP + col]; g0.w = Bs[(kk + 3) * MP + col];
      g1.x = Bs[(kk + 4) * MP + col]; g1.y = Bs[(kk + 5) * MP + col];
      g1.z = Bs[(kk + 6) * MP + col]; g1.w = Bs[(kk + 7) * MP + col];
    }
    ushort4 H0, L0, H1, L1;
    cvt4(g0, &H0, &L0); cvt4(g1, &H1, &L1);
    *(ushort4*)(FRAG + s * 8)            = H0;
    *(ushort4*)(FRAG + s * 8 + 4)        = H1;
    *(ushort4*)(FRAG + 4096 + s * 8)     = L0;
    *(ushort4*)(FRAG + 4096 + s * 8 + 4) = L1;
  }
  __syncthreads();  // mid
  {
    const int w = t >> 6, l = t & 63;
    if (w < NRT) {
      const int m = l & 15, g = l >> 4;
      v8s Ah[2], Al[2];
#pragma unroll
      for (int h = 0; h < 2; ++h) {
        const int row = w * 16 + m;
        const int kb = h * 32 + g * 8;
        const int e = row * MP + kb;
        float4 f0, f1;
        if (FA) {
          const float4 x0 = *(const float4*)(GX + e);
          const float4 x1 = *(const float4*)(GX + e + 4);
          const float4 y0 = *(const float4*)(GX2 + e);
          const float4 y1 = *(const float4*)(GX2 + e + 4);
          const float4 z0 = *(const float4*)(GX3 + e);
          const float4 z1 = *(const float4*)(GX3 + e + 4);
          f0.x = fmaf(cA.y, x0.x, fmaf(cA.z, y0.x, cA.w * z0.x));
          f0.y = fmaf(cA.y, x0.y, fmaf(cA.z, y0.y, cA.w * z0.y));
          f0.z = fmaf(cA.y, x0.z, fmaf(cA.z, y0.z, cA.w * z0.z));
          f0.w = fmaf(cA.y, x0.w, fmaf(cA.z, y0.w, cA.w * z0.w));
          f1.x = fmaf(cA.y, x1.x, fmaf(cA.z, y1.x, cA.w * z1.x));
          f1.y = fmaf(cA.y, x1.y, fmaf(cA.z, y1.y, cA.w * z1.y));
          f1.z = fmaf(cA.y, x1.z, fmaf(cA.z, y1.z, cA.w * z1.z));
          f1.w = fmaf(cA.y, x1.w, fmaf(cA.z, y1.w, cA.w * z1.w));
          if (row == kb + 0) f0.x += cA.x;
          if (row == kb + 1) f0.y += cA.x;
          if (row == kb + 2) f0.z += cA.x;
          if (row == kb + 3) f0.w += cA.x;
          if (row == kb + 4) f1.x += cA.x;
          if (row == kb + 5) f1.y += cA.x;
          if (row == kb + 6) f1.z += cA.x;
          if (row == kb + 7) f1.w += cA.x;
        } else {
          f0 = *(const float4*)(Ag + e);
          f1 = *(const float4*)(Ag + e + 4);
        }
        cvt8(f0, f1, &Ah[h], &Al[h]);
      }
#pragma unroll
      for (int Cc = 0; Cc < NCT; ++Cc) {
        const v8s Bh0 = *(const v8s*)(FRAG + ((Cc * 2 + 0) * 64 + l) * 8);
        const v8s Bh1 = *(const v8s*)(FRAG + ((Cc * 2 + 1) * 64 + l) * 8);
        const v8s Bl0 = *(const v8s*)(FRAG + 4096 + ((Cc * 2 + 0) * 64 + l) * 8);
        const v8s Bl1 = *(const v8s*)(FRAG + 4096 + ((Cc * 2 + 1) * 64 + l) * 8);
        const v4f z = {0.f, 0.f, 0.f, 0.f};
        v4f a0 = __builtin_amdgcn_mfma_f32_16x16x32_bf16(Ah[0], Bh0, z, 0, 0, 0);
        a0 = __builtin_amdgcn_mfma_f32_16x16x32_bf16(Ah[1], Bh1, a0, 0, 0, 0);
        v4f a1 = __builtin_amdgcn_mfma_f32_16x16x32_bf16(Ah[0], Bl0, z, 0, 0, 0);
        a1 = __builtin_amdgcn_mfma_f32_16x16x32_bf16(Ah[1], Bl1, a1, 0, 0, 0);
        v4f a2 = __builtin_amdgcn_mfma_f32_16x16x32_bf16(Al[0], Bh0, z, 0, 0, 0);
        a2 = __builtin_amdgcn_mfma_f32_16x16x32_bf16(Al[1], Bh1, a2, 0, 0, 0);
        const int col = Cc * 16 + m;
        const int r0 = rowbase + w * 16 + g * 4;
#pragma unroll
        for (int i = 0; i < 4; ++i) {
          float o = a0[i] + a1[i] + a2[i];
          if (FC) {
            const int rr = w * 16 + g * 4 + i;   // rowbase==0 for all FC uses
            const int eg = rr * MP + col;
            o = fmaf(cC.y, GX[eg], o);
            o = fmaf(cC.z, GX2[eg], o);
            o = fmaf(cC.w, GX3[eg], o);
            if (rr == col) o += cC.x;
          }
          Cd[(r0 + i) * cpitch + col] = o;
          if (Cd2) Cd2[(r0 + i) * MP + col] = o;
        }
      }
    }
  }
  __syncthreads();  // end
}

// vout = M*vin (rows of M, pitch MP). 4 lanes per row, shfl-xor reduce.
// half: vout = 0.5*(M*vin + vin). out2: extra row store. Entry+end barriers.
__device__ __forceinline__ void mv64row(const float* M, const float* vin,
                                        float* vout, float* out2, int half) {
  const int t = threadIdx.x;
  __syncthreads();
  const int w = t >> 6, l = t & 63;
  const int row = w * 16 + (l >> 2), q = l & 3;
  const float* mp = M + row * MP + q * 16;
  const float* vp = vin + q * 16;
  float p = 0.f;
#pragma unroll
  for (int j = 0; j < 16; j += 4) {
    const float4 m = *(const float4*)(mp + j);
    p = fmaf(m.x, vp[j + 0], p);
    p = fmaf(m.y, vp[j + 1], p);
    p = fmaf(m.z, vp[j + 2], p);
    p = fmaf(m.w, vp[j + 3], p);
  }
  p += __shfl_xor(p, 1);
  p += __shfl_xor(p, 2);
  if (q == 0) {
    float s = half ? 0.5f * (p + vin[row]) : p;
    vout[row] = s;
    if (out2) out2[row] = s;
  }
  __syncthreads();
}

// Horner-vector step: vout = pc.x*vB + pc.y*v1 + pc.z*v2 + pc.w*v3 + M*vin.
__device__ __forceinline__ void mv64row_phi(const float* M, const float* vin,
    float* vout, const float* vB, const float* v1, const float* v2,
    const float* v3, float4 pc) {
  const int t = threadIdx.x;
  __syncthreads();
  const int w = t >> 6, l = t & 63;
  const int row = w * 16 + (l >> 2), q = l & 3;
  const float* mp = M + row * MP + q * 16;
  const float* vp = vin + q * 16;
  float p = 0.f;
#pragma unroll
  for (int j = 0; j < 16; j += 4) {
    const float4 m = *(const float4*)(mp + j);
    p = fmaf(m.x, vp[j + 0], p);
    p = fmaf(m.y, vp[j + 1], p);
    p = fmaf(m.z, vp[j + 2], p);
    p = fmaf(m.w, vp[j + 3], p);
  }
  p += __shfl_xor(p, 1);
  p += __shfl_xor(p, 2);
  if (q == 0)
    vout[row] = fmaf(pc.x, vB[row], fmaf(pc.y, v1[row],
                fmaf(pc.z, v2[row], fmaf(pc.w, v3[row], p))));
  __syncthreads();
}

// vout = M^T*vin. 4 lanes per output col, shfl-xor reduce. Entry+end barriers.
__device__ __forceinline__ void mv64colT(const float* M, const float* vin,
                                         float* vout, float* out2) {
  const int t = threadIdx.x;
  __syncthreads();
  const int w = t >> 6, l = t & 63;
  const int col = w * 16 + (l >> 2), q = l & 3;
  float p = 0.f;
#pragma unroll
  for (int j = 0; j < 16; ++j)
    p = fmaf(M[(q * 16 + j) * MP + col], vin[q * 16 + j], p);
  p += __shfl_xor(p, 1);
  p += __shfl_xor(p, 2);
  if (q == 0) {
    vout[col] = p;
    if (out2) out2[col] = p;
  }
  __syncthreads();
}

__global__ __launch_bounds__(NT) void s4_setup(const float* __restrict__ u,
    const float* __restrict__ A, const float* __restrict__ Bv,
    const float* __restrict__ Cv, const float* __restrict__ logdt,
    float* __restrict__ ws) {
  if (blockIdx.x > 0) {
    const int idx = (blockIdx.x - 1) * NT + threadIdx.x;  // 0..16383
    ws[4096 + idx] = u[(size_t)idx * 1024];
    return;
  }
  // 6 matrix slots (104.4KB) + FRAG 16KB + vecs ~ 123KB LDS.
  __shared__ __align__(16) float S0[MB];
  __shared__ __align__(16) float SX[MB];
  __shared__ __align__(16) float SX2[MB];
  __shared__ __align__(16) float SX3[MB];
  __shared__ __align__(16) float SU0[MB];
  __shared__ __align__(16) float SU1[MB];
  __shared__ __align__(16) unsigned short FRAG[8192];
  __shared__ float vB[64], v1[64], v2[64], v3[64], va[64], vb[64], vg[64];
  __shared__ int s_s;
  float* vscr = (float*)FRAG;  // overlay: only used by the 1-norm (pre-mm)

  const int t = threadIdx.x;
  float* kbuf = ws;
  float* SBRT = SU0;  // reused after Horner frees U0
  float* SCQT = SU1;  // reused after Horner frees U1
  const float dt = expf(logdt[0]);
  const float4 zf4 = make_float4(0.f, 0.f, 0.f, 0.f);

  const float invf[17] = {1.f, 1.f, 1.f / 2.f, 1.f / 6.f, 1.f / 24.f, 1.f / 120.f,
                          1.f / 720.f, 1.f / 5040.f, 1.f / 40320.f, 1.f / 362880.f,
                          1.f / 3628800.f, 1.f / 39916800.f, 1.f / 479001600.f,
                          1.f / 6.2270208e9f, 1.f / 8.71782912e10f,
                          1.f / 1.307674368e12f, 1.f / 2.0922789888e13f};

  // ---- 1-norm of dt*A -> s (theta = 2) ----
  {
    const int j = t & 63, w = t >> 6;
    float p = 0.f;
#pragma unroll
    for (int ii = 0; ii < 16; ++ii) p += fabsf(A[(w * 16 + ii) * 64 + j]);
    vscr[t] = p;
    __syncthreads();
    if (t < 64) {
      float cs = vscr[t] + vscr[64 + t] + vscr[128 + t] + vscr[192 + t];
      cs *= dt;
#pragma unroll
      for (int off = 32; off > 0; off >>= 1) cs = fmaxf(cs, __shfl_xor(cs, off));
      if (t == 0) {
        int s = 0;
        while (cs > 2.0f && s < 30) { cs *= 0.5f; ++s; }
        s_s = s;
      }
    }
    __syncthreads();
  }
  const int sq = s_s;
  const float scl = ldexpf(dt, -sq);

  // ---- X -> S0 and SX; vB ----
  {
    const int r = t >> 2, cb = (t & 3) * 16;
#pragma unroll
    for (int j = 0; j < 16; j += 4) {
      const float4 a4 = *(const float4*)(A + r * 64 + cb + j);
      float4 x;
      x.x = a4.x * scl; x.y = a4.y * scl; x.z = a4.z * scl; x.w = a4.w * scl;
      *(float4*)(S0 + r * MP + cb + j) = x;
      *(float4*)(SX + r * MP + cb + j) = x;
    }
    if (t < 64) vB[t] = Bv[t];
    __syncthreads();
  }

  // ---- powers: X2 (S0, +SX2), X3 (SX3), X4 (S0 in-place) ----
  mm<4,4,0,0,0>(S0, S0, S0, MP, SX2, 0, SX, SX2, SX3, zf4, zf4, FRAG);   // X2
  mm<4,4,0,0,0>(SX, S0, SX3, MP, nullptr, 0, SX, SX2, SX3, zf4, zf4, FRAG); // X3
  mm<4,4,0,0,0>(S0, S0, S0, MP, nullptr, 0, SX, SX2, SX3, zf4, zf4, FRAG);  // X4

  // ---- phi1(X)*B via PS on vectors (deg-15, groups of 4 in X4) ----
  mv64row(SX,  vB, v1, nullptr, 0);
  mv64row(SX2, vB, v2, nullptr, 0);
  mv64row(SX3, vB, v3, nullptr, 0);
  if (t < 64)
    va[t] = invf[13] * vB[t] + invf[14] * v1[t] + invf[15] * v2[t] + invf[16] * v3[t];
  __syncthreads();
  mv64row_phi(S0, va, vb, vB, v1, v2, v3,
              make_float4(invf[9], invf[10], invf[11], invf[12]));
  mv64row_phi(S0, vb, va, vB, v1, v2, v3,
              make_float4(invf[5], invf[6], invf[7], invf[8]));
  mv64row_phi(S0, va, vg, vB, v1, v2, v3,
              make_float4(invf[1], invf[2], invf[3], invf[4]));

  // ---- e^X: Taylor-15 PS Horner, buildG fused (FA/FC) ----
  // SU1 = G2 + G3*X4 ; SU0 = G1 + SU1*X4 ; S0 = G0 + SU0*X4 = e^X
  mm<4,4,0,1,1>(nullptr, S0, SU1, MP, nullptr, 0, SX, SX2, SX3,
                make_float4(invf[12], invf[13], invf[14], invf[15]),
                make_float4(invf[8], invf[9], invf[10], invf[11]), FRAG);
  mm<4,4,0,0,1>(SU1, S0, SU0, MP, nullptr, 0, SX, SX2, SX3, zf4,
                make_float4(invf[4], invf[5], invf[6], invf[7]), FRAG);
  mm<4,4,0,0,1>(SU0, S0, S0, MP, nullptr, 0, SX, SX2, SX3, zf4,
                make_float4(invf[0], invf[1], invf[2], invf[3]), FRAG);
  // S0 = e^X

  // ---- squarings + phi1 doubling: g <- (F+I)g/2 (ping-pong vg/va) ----
  float* vcur = vg;
  float* vnxt = va;
  for (int it = 0; it < sq; ++it) {
    mv64row(S0, vcur, vnxt, nullptr, 1);  // vnxt = 0.5*(S0*vcur + vcur)
    { float* tmp = vcur; vcur = vnxt; vnxt = tmp; }
    mm<4,4,0,0,0>(S0, S0, S0, MP, nullptr, 0, SX, SX2, SX3, zf4, zf4, FRAG);
  }
  // S0 = Abar, vcur = phi1 vector

  // ---- BRT rows 0..15: bbar then Abar^r bbar (row store folded into mv) ----
  if (t < 64) {
    const float bb = dt * vcur[t];
    v1[t] = bb;
    SBRT[t] = bb;
  }
  __syncthreads();
  {
    float* vc = v1; float* vn = v2;
    for (int r = 1; r < 16; ++r) {
      mv64row(S0, vc, vn, SBRT + r * MP, 0);
      float* tmp = vc; vc = vn; vn = tmp;
    }
  }

  // ---- P-chain (in-place) + BRT widenings ----
  mm<4,4,0,0,0>(S0, S0, S0, MP, nullptr, 0, SX, SX2, SX3, zf4, zf4, FRAG); // P2
  mm<4,4,0,0,0>(S0, S0, S0, MP, nullptr, 0, SX, SX2, SX3, zf4, zf4, FRAG); // P4
  mm<4,4,0,0,0>(S0, S0, S0, MP, nullptr, 0, SX, SX2, SX3, zf4, zf4, FRAG); // P8
  mm<4,4,0,0,0>(S0, S0, S0, MP, nullptr, 0, SX, SX2, SX3, zf4, zf4, FRAG); // P16
  mm<1,4,1,0,0>(SBRT, S0, SBRT, MP, nullptr, 16, SX, SX2, SX3, zf4, zf4, FRAG); // r16:32
  mm<4,4,0,0,0>(S0, S0, S0, MP, nullptr, 0, SX, SX2, SX3, zf4, zf4, FRAG); // P32
  mm<2,4,1,0,0>(SBRT, S0, SBRT, MP, nullptr, 32, SX, SX2, SX3, zf4, zf4, FRAG); // r32:64
  mm<4,4,0,0,0>(S0, S0, S0, MP, nullptr, 0, SX, SX2, SX3, zf4, zf4, FRAG); // P64

  // ---- CQT rows 0..15: c then (P64^T)^q c (row store folded into mv) ----
  if (t < 64) {
    const float cc = Cv[t];
    v1[t] = cc;
    SCQT[t] = cc;
  }
  __syncthreads();
  {
    float* vc = v1; float* vn = v2;
    for (int qx = 1; qx < 16; ++qx) {
      mv64colT(S0, vc, vn, SCQT + qx * MP);
      float* tmp = vc; vc = vn; vn = tmp;
    }
  }

  // ---- A-chain (in-place) + CQT widenings ----
  mm<4,4,0,0,0>(S0, S0, S0, MP, nullptr, 0, SX, SX2, SX3, zf4, zf4, FRAG); // A128
  mm<4,4,0,0,0>(S0, S0, S0, MP, nullptr, 0, SX, SX2, SX3, zf4, zf4, FRAG); // A256
  mm<4,4,0,0,0>(S0, S0, S0, MP, nullptr, 0, SX, SX2, SX3, zf4, zf4, FRAG); // A512
  mm<4,4,0,0,0>(S0, S0, S0, MP, nullptr, 0, SX, SX2, SX3, zf4, zf4, FRAG); // A1024
  mm<1,4,0,0,0>(SCQT, S0, SCQT, MP, nullptr, 16, SX, SX2, SX3, zf4, zf4, FRAG); // r16:32
  mm<4,4,0,0,0>(S0, S0, S0, MP, nullptr, 0, SX, SX2, SX3, zf4, zf4, FRAG); // A2048
  mm<2,4,0,0,0>(SCQT, S0, SCQT, MP, nullptr, 32, SX, SX2, SX3, zf4, zf4, FRAG); // r32:64

  // ---- k[q*64+r] = sum_i CQT[q][i]*BRT[r][i] (only global write) ----
  mm<4,4,1,0,0>(SCQT, SBRT, kbuf, 64, nullptr, 0, SX, SX2, SX3, zf4, zf4, FRAG);
}

// Fused conv + broadcast. 4096 blocks x 256 threads; block computes y[t0..t0+3]
// for one batch, then streams 4 rows x 1024 cols of broadcast stores.
// Conv: aligned sliding-window float4: y[t0+d] += sum_i k[b0+d-i]*u[s0+i],
// b0=t0-s0 (mult of 4); k via two aligned float4 (k1 zeroed at b0==0).
__global__ __launch_bounds__(256) void s4_out(const float* __restrict__ ws,
                                              const float* __restrict__ Dp,
                                              float* __restrict__ out) {
  const int bid = blockIdx.x;
  const int b = bid >> 10;
  const int t0 = (bid & 1023) << 2;
  const float* kb = ws;
  const float* ub = ws + 4096 + (b << 12);
  const int tid = threadIdx.x;

  float a0 = 0.f, a1 = 0.f, a2 = 0.f, a3 = 0.f;
  for (int s0 = tid << 2; s0 <= t0; s0 += 1024) {
    const float4 uv = *(const float4*)(ub + s0);
    const int b0 = t0 - s0;
    const float4 k0 = *(const float4*)(kb + b0);
    float4 k1 = make_float4(0.f, 0.f, 0.f, 0.f);
    if (b0 >= 4) k1 = *(const float4*)(kb + b0 - 4);
    a0 = fmaf(k0.x, uv.x, a0);
    a0 = fmaf(k1.w, uv.y, a0);
    a0 = fmaf(k1.z, uv.z, a0);
    a0 = fmaf(k1.y, uv.w, a0);
    a1 = fmaf(k0.y, uv.x, a1);
    a1 = fmaf(k0.x, uv.y, a1);
    a1 = fmaf(k1.w, uv.z, a1);
    a1 = fmaf(k1.z, uv.w, a1);
    a2 = fmaf(k0.z, uv.x, a2);
    a2 = fmaf(k0.y, uv.y, a2);
    a2 = fmaf(k0.x, uv.z, a2);
    a2 = fmaf(k1.w, uv.w, a2);
    a3 = fmaf(k0.w, uv.x, a3);
    a3 = fmaf(k0.z, uv.y, a3);
    a3 = fmaf(k0.y, uv.z, a3);
    a3 = fmaf(k0.x, uv.w, a3);
  }
#pragma unroll
  for (int off = 32; off > 0; off >>= 1) {
    a0 += __shfl_xor(a0, off);
    a1 += __shfl_xor(a1, off);
    a2 += __shfl_xor(a2, off);
    a3 += __shfl_xor(a3, off);
  }
  __shared__ float red[4][4];
  __shared__ float sy[4];
  if ((tid & 63) == 0) {
    const int w = tid >> 6;
    red[0][w] = a0; red[1][w] = a1; red[2][w] = a2; red[3][w] = a3;
  }
  __syncthreads();
  if (tid < 4)
    sy[tid] = red[tid][0] + red[tid][1] + red[tid][2] + red[tid][3] +
              Dp[0] * ub[t0 + tid];
  __syncthreads();
  const int row = tid >> 6, lx = tid & 63;
  const float y = sy[row];
  const v4f y4 = {y, y, y, y};
  v4f* dst = (v4f*)(out + ((size_t)(b << 12) + t0 + row) * 1024);
  __builtin_nontemporal_store(y4, dst + lx);
  __builtin_nontemporal_store(y4, dst + lx + 64);
  __builtin_nontemporal_store(y4, dst + lx + 128);
  __builtin_nontemporal_store(y4, dst + lx + 192);
}

extern "C" void kernel_launch(void* const* d_in, const int* in_sizes, int n_in,
                              void* d_out, int out_size, void* d_ws, size_t ws_size,
                              hipStream_t stream) {
  const float* u  = (const float*)d_in[0];
  const float* A  = (const float*)d_in[1];
  const float* B  = (const float*)d_in[2];
  const float* C  = (const float*)d_in[3];
  const float* D  = (const float*)d_in[4];
  const float* ld = (const float*)d_in[5];
  float* ws = (float*)d_ws;  // needs >= 81920 bytes

  s4_setup<<<65, NT, 0, stream>>>(u, A, B, C, ld, ws);
  s4_out<<<4096, 256, 0, stream>>>(ws, D, (float*)d_out);
}